// Round 7
// baseline (218.587 us; speedup 1.0000x reference)
//
#include <hip/hip_runtime.h>
#include <hip/hip_bf16.h>

#define HID 16
#define SB_BITS 11
#define SBLK 2048                      // dst per top-level block
#define NBA_MAX 52                     // max bins pass A (N<=106k)
#define CSTRIDE 257                    // cntP per-bin stride (257%32==1 -> bank spread)
#define PT 256
#define PT_K 16
#define PT_EDGES (PT * PT_K)           // 4096 edges per sort tile
#define ROWP 65                        // padded slot row in agg kernels
#define GSTRIDE 16                     // gcurA: one counter per 64B line

// ---------------- init: zero all cursors ----------------
__global__ void k_init(int* __restrict__ p, int n) {
    int i = blockIdx.x * blockDim.x + threadIdx.x;
    if (i < n) p[i] = 0;
}

// ---------------- pass A: sort by dst>>11 (49 bins), atomic-free ranking -----
// payload out: (dloc11 << 17) | src17
__global__ void __launch_bounds__(PT)
k_sortA(const int* __restrict__ src, const int* __restrict__ dst,
        unsigned* __restrict__ outb, int* __restrict__ gcurA,
        int E, int nb, int capA) {
    __shared__ int cntP[NBA_MAX * CSTRIDE];
    __shared__ int chunkTot[NBA_MAX * 4];
    __shared__ int binTot[NBA_MAX];
    __shared__ int pos[NBA_MAX];
    __shared__ int gbase[NBA_MAX];
    __shared__ unsigned reorder[PT_EDGES];
    __shared__ unsigned char bbk[PT_EDGES];
    int tid = threadIdx.x, w = tid >> 6, l = tid & 63;
    int tb = blockIdx.x * PT_EDGES;
    int nE = min(PT_EDGES, E - tb);
    for (int b = 0; b < nb; b++) cntP[b * CSTRIDE + tid] = 0;
    __syncthreads();
    unsigned pk[PT_K]; int rr[PT_K]; int rk[PT_K];
#pragma unroll
    for (int k = 0; k < PT_K; k++) {
        int e = tb + k * PT + tid;
        rr[k] = -1;
        if (e < E) {
            int s = src[e], d = dst[e];
            int b = d >> SB_BITS;
            rr[k] = b;
            pk[k] = ((unsigned)(d & (SBLK - 1)) << 17) | (unsigned)s;
            int idx = b * CSTRIDE + tid;
            int o = cntP[idx]; cntP[idx] = o + 1; rk[k] = o;   // private slot, no race
        }
    }
    __syncthreads();
    // per-wave chunk scan: wave w scans tids [64w,64w+64) for bin l
    if (l < nb) {
        int acc = 0, base = l * CSTRIDE + (w << 6);
        for (int t = 0; t < 64; t++) { int v = cntP[base + t]; cntP[base + t] = acc; acc += v; }
        chunkTot[l * 4 + w] = acc;
    }
    __syncthreads();
    if (tid < nb) {
        int acc = 0;
        for (int ww = 0; ww < 4; ww++) { int v = chunkTot[tid * 4 + ww]; chunkTot[tid * 4 + ww] = acc; acc += v; }
        binTot[tid] = acc;
    }
    __syncthreads();
    if (tid == 0) { int acc = 0; for (int b = 0; b < nb; b++) { pos[b] = acc; acc += binTot[b]; } }
    __syncthreads();
    if (tid < nb && binTot[tid] > 0)
        gbase[tid] = atomicAdd(&gcurA[tid * GSTRIDE], binTot[tid]);
    __syncthreads();
#pragma unroll
    for (int k = 0; k < PT_K; k++) {
        if (rr[k] >= 0) {
            int b = rr[k];
            int idx = pos[b] + chunkTot[b * 4 + w] + cntP[b * CSTRIDE + tid] + rk[k];
            reorder[idx] = pk[k];
            bbk[idx] = (unsigned char)b;
        }
    }
    __syncthreads();
    for (int idx = tid; idx < nE; idx += PT) {
        int b = bbk[idx];
        int g = gbase[b] + (idx - pos[b]);
        if (g < capA) outb[(size_t)b * capA + g] = reorder[idx];
    }
}

// ---------------- passes B1/B2: refine 2048->128->16 dst granularity ---------
// PASS 1: bin = p>>24 (16 bins), out payload = p & 0xFFFFFF (dloc7<<17|src)
// PASS 2: bin = p>>21 (8 bins),  out payload = (src17<<4)|d4
template<int NB, int PASS>
__global__ void __launch_bounds__(PT)
k_sortB(const unsigned* __restrict__ inb, const int* __restrict__ incur, int inCurStride,
        unsigned* __restrict__ outb, int* __restrict__ outcur,
        int capIn, int capOut, int tilesPerRow) {
    int row = blockIdx.x / tilesPerRow;
    int tile = blockIdx.x - row * tilesPerRow;
    int cnt_row = min(incur[row * inCurStride], capIn);
    int tb = tile * PT_EDGES;
    if (tb >= cnt_row) return;                 // block-uniform
    int nE = min(PT_EDGES, cnt_row - tb);
    __shared__ int cntP[NB * CSTRIDE];
    __shared__ int chunkTot[NB * 4];
    __shared__ int binTot[NB];
    __shared__ int pos[NB];
    __shared__ int gbase[NB];
    __shared__ unsigned reorder[PT_EDGES];
    __shared__ unsigned char bbk[PT_EDGES];
    int tid = threadIdx.x, w = tid >> 6, l = tid & 63;
    for (int b = 0; b < NB; b++) cntP[b * CSTRIDE + tid] = 0;
    __syncthreads();
    const unsigned* in = inb + (size_t)row * capIn + tb;
    unsigned pk[PT_K]; int rr[PT_K]; int rk[PT_K];
#pragma unroll
    for (int k = 0; k < PT_K; k++) {
        int e = k * PT + tid;
        rr[k] = -1;
        if (e < nE) {
            unsigned p = in[e];
            int b = (PASS == 1) ? (int)(p >> 24) : (int)(p >> 21);
            rr[k] = b;
            pk[k] = (PASS == 1) ? (p & 0x00FFFFFFu)
                                : (((p & 0x1FFFFu) << 4) | ((p >> 17) & 15u));
            int idx = b * CSTRIDE + tid;
            int o = cntP[idx]; cntP[idx] = o + 1; rk[k] = o;
        }
    }
    __syncthreads();
    if (l < NB) {
        int acc = 0, base = l * CSTRIDE + (w << 6);
        for (int t = 0; t < 64; t++) { int v = cntP[base + t]; cntP[base + t] = acc; acc += v; }
        chunkTot[l * 4 + w] = acc;
    }
    __syncthreads();
    if (tid < NB) {
        int acc = 0;
        for (int ww = 0; ww < 4; ww++) { int v = chunkTot[tid * 4 + ww]; chunkTot[tid * 4 + ww] = acc; acc += v; }
        binTot[tid] = acc;
    }
    __syncthreads();
    if (tid == 0) { int acc = 0; for (int b = 0; b < NB; b++) { pos[b] = acc; acc += binTot[b]; } }
    __syncthreads();
    if (tid < NB && binTot[tid] > 0)
        gbase[tid] = atomicAdd(&outcur[row * NB + tid], binTot[tid]);
    __syncthreads();
#pragma unroll
    for (int k = 0; k < PT_K; k++) {
        if (rr[k] >= 0) {
            int b = rr[k];
            int idx = pos[b] + chunkTot[b * 4 + w] + cntP[b * CSTRIDE + tid] + rk[k];
            reorder[idx] = pk[k];
            bbk[idx] = (unsigned char)b;
        }
    }
    __syncthreads();
    for (int idx = tid; idx < nE; idx += PT) {
        int b = bbk[idx];
        int g = gbase[b] + (idx - pos[b]);
        if (g < capOut) outb[(size_t)(row * NB + b) * capOut + g] = reorder[idx];
    }
}

// ---------------- agg1 + fused encode ---------------------------------------
// u1=Wp_rel·wd_rel, u2=Wp_rel·wd_root, v1=Wp_root·wd_rel, v2=Wp_root·wd_root
__global__ void __launch_bounds__(256)
k_agg1enc(const unsigned* __restrict__ bk2, const int* __restrict__ gcurB2,
          const float* __restrict__ x,
          const float* __restrict__ ewrel, const float* __restrict__ ewroot,
          const float* __restrict__ eb,
          const float* __restrict__ pwrel, const float* __restrict__ pwroot,
          const float* __restrict__ dwrel, const float* __restrict__ dwroot,
          float* __restrict__ SAB, float* __restrict__ G1, float* __restrict__ G2,
          int capSub, int N) {
    __shared__ float P[4 * 16 * ROWP];
    __shared__ float su1[HID], su2[HID], sv1[HID], sv2[HID];
    __shared__ float swr[HID], swo[HID], sbb[HID];
    int t = threadIdx.x;
    if (t < 64) {
        int k = t & 15, w = t >> 4;
        const float* M  = (w < 2) ? pwrel : pwroot;
        const float* vv = ((w & 1) == 0) ? dwrel : dwroot;
        float acc = 0.f;
        for (int h = 0; h < HID; h++) acc += M[k * HID + h] * vv[h];
        if (w == 0) su1[k] = acc;
        else if (w == 1) su2[k] = acc;
        else if (w == 2) sv1[k] = acc;
        else sv2[k] = acc;
    }
    if (t < HID) { swr[t] = ewrel[t]; swo[t] = ewroot[t]; sbb[t] = eb[t]; }
    int wv = t >> 6, lane = t & 63;
    int q = blockIdx.x * 4 + wv;
    float* p = P + wv * 16 * ROWP;
#pragma unroll
    for (int d = 0; d < 16; d++) p[d * ROWP + lane] = 0.f;
    __syncthreads();
    int cnt = min(gcurB2[q], capSub);
    const unsigned* bk = bk2 + (size_t)q * capSub;
    int e = lane;
    for (; e + 64 < cnt; e += 128) {
        unsigned pk0 = bk[e], pk1 = bk[e + 64];
        float v0 = x[pk0 >> 4], v1 = x[pk1 >> 4];
        p[(int)(pk0 & 15) * ROWP + lane] += v0;
        p[(int)(pk1 & 15) * ROWP + lane] += v1;
    }
    if (e < cnt) { unsigned pk = bk[e]; p[(int)(pk & 15) * ROWP + lane] += x[pk >> 4]; }
    __builtin_amdgcn_wave_barrier();
    int d = lane & 15, c0 = (lane >> 4) * 16;
    float s = 0.f;
#pragma unroll
    for (int k = 0; k < 16; k++) s += p[d * ROWP + c0 + k];
    s += __shfl_xor(s, 16);
    s += __shfl_xor(s, 32);
    if (lane < 16) {
        int n = q * 16 + lane;
        if (n < N) {
            float a1 = s, xi = x[n];
            float sa = 0.f, sb = 0.f, g1 = 0.f, g2 = 0.f;
#pragma unroll
            for (int h = 0; h < HID; h++) {
                float z = fmaxf(fmaf(a1, swr[h], fmaf(xi, swo[h], sbb[h])), 0.f);
                sa = fmaf(z, su1[h], sa);
                sb = fmaf(z, su2[h], sb);
                g1 = fmaf(z, sv1[h], g1);
                g2 = fmaf(z, sv2[h], g2);
            }
            ((float2*)SAB)[n] = make_float2(sa, sb);
            G1[n] = g1; G2[n] = g2;
        }
    }
}

// ---------------- agg2 + fused mid ------------------------------------------
__global__ void __launch_bounds__(256)
k_agg2mid(const unsigned* __restrict__ bk2, const int* __restrict__ gcurB2,
          const float* __restrict__ SAB,
          const float* __restrict__ G1, const float* __restrict__ G2,
          const float* __restrict__ pb, const float* __restrict__ dwrel,
          const float* __restrict__ dwroot, const float* __restrict__ db,
          float* __restrict__ BETA, float* __restrict__ R,
          int capSub, int N) {
    __shared__ float P[4 * 2 * 16 * ROWP];
    __shared__ float sc1, sc2, sbd;
    int t = threadIdx.x;
    if (t == 0) {
        float c1 = 0.f, c2 = 0.f;
        for (int h = 0; h < HID; h++) { c1 += pb[h] * dwrel[h]; c2 += pb[h] * dwroot[h]; }
        sc1 = c1; sc2 = c2; sbd = db[0];
    }
    int wv = t >> 6, lane = t & 63;
    int q = blockIdx.x * 4 + wv;
    float* pa = P + wv * 2 * 16 * ROWP;
    float* pbn = pa + 16 * ROWP;
#pragma unroll
    for (int d = 0; d < 16; d++) { pa[d * ROWP + lane] = 0.f; pbn[d * ROWP + lane] = 0.f; }
    __syncthreads();
    int cnt = min(gcurB2[q], capSub);
    const unsigned* bk = bk2 + (size_t)q * capSub;
    const float2* v2 = (const float2*)SAB;
    int e = lane;
    for (; e + 64 < cnt; e += 128) {
        unsigned pk0 = bk[e], pk1 = bk[e + 64];
        float2 v0 = v2[pk0 >> 4], v1 = v2[pk1 >> 4];
        int a0 = (int)(pk0 & 15) * ROWP + lane;
        int a1 = (int)(pk1 & 15) * ROWP + lane;
        pa[a0] += v0.x; pbn[a0] += v0.y;
        pa[a1] += v1.x; pbn[a1] += v1.y;
    }
    if (e < cnt) {
        unsigned pk = bk[e];
        float2 v = v2[pk >> 4];
        int a = (int)(pk & 15) * ROWP + lane;
        pa[a] += v.x; pbn[a] += v.y;
    }
    __builtin_amdgcn_wave_barrier();
    int d = lane & 15, c0 = (lane >> 4) * 16;
    float sa = 0.f, sb = 0.f;
#pragma unroll
    for (int k = 0; k < 16; k++) {
        sa += pa[d * ROWP + c0 + k];
        sb += pbn[d * ROWP + c0 + k];
    }
    sa += __shfl_xor(sa, 16); sa += __shfl_xor(sa, 32);
    sb += __shfl_xor(sb, 16); sb += __shfl_xor(sb, 32);
    if (lane < 16) {
        int n = q * 16 + lane;
        if (n < N) {
            BETA[n] = sa + G1[n] + sc1;
            R[n]    = sb + G2[n] + sc2 + sbd;
        }
    }
}

// ---------------- agg3 + fused final: out = relu(agg(BETA) + R) --------------
__global__ void __launch_bounds__(256)
k_agg1f(const unsigned* __restrict__ bk2, const int* __restrict__ gcurB2,
        const float* __restrict__ val, const float* __restrict__ R,
        float* __restrict__ out, int capSub, int N) {
    __shared__ float P[4 * 16 * ROWP];
    int wv = threadIdx.x >> 6, lane = threadIdx.x & 63;
    int q = blockIdx.x * 4 + wv;
    float* p = P + wv * 16 * ROWP;
#pragma unroll
    for (int d = 0; d < 16; d++) p[d * ROWP + lane] = 0.f;
    int cnt = min(gcurB2[q], capSub);
    const unsigned* bk = bk2 + (size_t)q * capSub;
    int e = lane;
    for (; e + 64 < cnt; e += 128) {
        unsigned pk0 = bk[e], pk1 = bk[e + 64];
        float v0 = val[pk0 >> 4], v1 = val[pk1 >> 4];
        p[(int)(pk0 & 15) * ROWP + lane] += v0;
        p[(int)(pk1 & 15) * ROWP + lane] += v1;
    }
    if (e < cnt) { unsigned pk = bk[e]; p[(int)(pk & 15) * ROWP + lane] += val[pk >> 4]; }
    __builtin_amdgcn_wave_barrier();
    int d = lane & 15, c0 = (lane >> 4) * 16;
    float s = 0.f;
#pragma unroll
    for (int k = 0; k < 16; k++) s += p[d * ROWP + c0 + k];
    s += __shfl_xor(s, 16);
    s += __shfl_xor(s, 32);
    if (lane < 16) {
        int n = q * 16 + lane;
        if (n < N) out[n] = fmaxf(s + R[n], 0.f);
    }
}

// ---------------- launch ----------------
extern "C" void kernel_launch(void* const* d_in, const int* in_sizes, int n_in,
                              void* d_out, int out_size, void* d_ws, size_t ws_size,
                              hipStream_t stream) {
    const float* x      = (const float*)d_in[0];
    const int*   ei     = (const int*)d_in[1];
    const float* ewrel  = (const float*)d_in[2];
    const float* ewroot = (const float*)d_in[3];
    const float* eb     = (const float*)d_in[4];
    const float* pwrel  = (const float*)d_in[5];
    const float* pwroot = (const float*)d_in[6];
    const float* pb     = (const float*)d_in[7];
    const float* dwrel  = (const float*)d_in[8];
    const float* dwroot = (const float*)d_in[9];
    const float* db     = (const float*)d_in[10];
    float* out = (float*)d_out;

    const int N = in_sizes[0];
    const int E = in_sizes[1] / 2;
    const int* src = ei;
    const int* dst = ei + E;

    const int nbA = (N + SBLK - 1) >> SB_BITS;                 // 49
    int capA = ((E / nbA + 2048) + PT_EDGES - 1) & ~(PT_EDGES - 1);  // 69632
    const int tilesB1 = capA / PT_EDGES;                       // 17
    const int nRow1 = nbA * 16;                                // 784
    int capB1 = ((E / nRow1 + 640) + 3) & ~3;                  // ~4724 (10 sigma)
    const int tilesB2 = (capB1 + PT_EDGES - 1) / PT_EDGES;     // 2
    const int nq = nbA * 128;                                  // 6272 sub-buckets
    int capSub = ((E / nq + 226) + 3) & ~3;                    // ~736 (10 sigma)

    // workspace layout (4-byte words)
    size_t off = 0;
    int* gcurA  = (int*)d_ws;                  off += (size_t)nbA * GSTRIDE;  // 784
    int* gcurB1 = (int*)d_ws + off;            off += nRow1;                  // 784
    int* gcurB2 = (int*)d_ws + off;            off += nq;                     // 6272
    const int zeroWords = (int)off;            // all cursors contiguous
    off = (off + 255) & ~(size_t)255;
    unsigned* bucketsA  = (unsigned*)d_ws + off; off += (size_t)nbA * capA;
    unsigned* bucketsB1 = (unsigned*)d_ws + off; off += (size_t)nRow1 * capB1;
    unsigned* bucketsB2 = (unsigned*)d_ws + off; off += (size_t)nq * capSub;
    float* SAB  = (float*)d_ws + off;          off += (size_t)2 * N;
    float* G1   = (float*)d_ws + off;          off += N;
    float* G2   = (float*)d_ws + off;          off += N;
    float* BETA = (float*)d_ws + off;          off += N;
    float* R    = (float*)d_ws + off;          off += N;

    const int ntilesA = (E + PT_EDGES - 1) / PT_EDGES;         // 782
    const int aggBlocks = nq / 4;                              // 1568

    hipLaunchKernelGGL(k_init, dim3((zeroWords + 255) / 256), dim3(256), 0, stream,
                       gcurA, zeroWords);
    hipLaunchKernelGGL(k_sortA, dim3(ntilesA), dim3(PT), 0, stream,
                       src, dst, bucketsA, gcurA, E, nbA, capA);
    hipLaunchKernelGGL((k_sortB<16, 1>), dim3(nbA * tilesB1), dim3(PT), 0, stream,
                       bucketsA, gcurA, GSTRIDE, bucketsB1, gcurB1, capA, capB1, tilesB1);
    hipLaunchKernelGGL((k_sortB<8, 2>), dim3(nRow1 * tilesB2), dim3(PT), 0, stream,
                       bucketsB1, gcurB1, 1, bucketsB2, gcurB2, capB1, capSub, tilesB2);

    // layer 1 agg + encode (writes SAB, G1, G2)
    hipLaunchKernelGGL(k_agg1enc, dim3(aggBlocks), dim3(256), 0, stream,
                       bucketsB2, gcurB2, x, ewrel, ewroot, eb, pwrel, pwroot,
                       dwrel, dwroot, SAB, G1, G2, capSub, N);
    // layer 2 agg + mid (writes BETA, R)
    hipLaunchKernelGGL(k_agg2mid, dim3(aggBlocks), dim3(256), 0, stream,
                       bucketsB2, gcurB2, SAB, G1, G2, pb, dwrel, dwroot, db,
                       BETA, R, capSub, N);
    // layer 3 agg + final
    hipLaunchKernelGGL(k_agg1f, dim3(aggBlocks), dim3(256), 0, stream,
                       bucketsB2, gcurB2, BETA, R, out, capSub, N);
}

// Round 8
// 182.670 us; speedup vs baseline: 1.1966x; 1.1966x over previous
//
#include <hip/hip_runtime.h>
#include <hip/hip_bf16.h>

#define HID 16
#define SB_BITS 11
#define SBLK (1 << SB_BITS)            // 2048 dst per block-range
#define SUBS 128                       // sub-buckets per range (16 dst each)
#define NBMAX 64
#define GSTRIDE 16                     // gcurA: one counter per 64B line
#define PT_THREADS 256
#define PT_K 16
#define PT_EDGES (PT_THREADS * PT_K)   // 4096 edges per partition tile
#define ROWP 65                        // padded slot-row (16 rows of 65 words)

// ---------------- init: zero cursors ----------------
__global__ void k_init(int* __restrict__ p, int n) {
    int i = blockIdx.x * blockDim.x + threadIdx.x;
    if (i < n) p[i] = 0;
}

// ---------------- pass A: bin edges by dst-block; payload (dloc11<<17)|src17 --
__global__ void k_passA(const int* __restrict__ src, const int* __restrict__ dst,
                        unsigned* __restrict__ bucketsA, int* __restrict__ gcurA,
                        int E, int nb, int capA) {
    __shared__ int cnt[NBMAX];
    __shared__ int pos[NBMAX];
    __shared__ int gbase[NBMAX];
    __shared__ unsigned reorder[PT_EDGES];
    __shared__ unsigned char bbk[PT_EDGES];
    int tb = blockIdx.x * PT_EDGES;
    int nE = min(PT_EDGES, E - tb);
    if (threadIdx.x < nb) cnt[threadIdx.x] = 0;
    __syncthreads();
    int kk[PT_K]; int rk[PT_K]; unsigned pk[PT_K];
#pragma unroll
    for (int k = 0; k < PT_K; k++) {
        int e = tb + k * PT_THREADS + threadIdx.x;
        if (e < E) {
            int s = src[e], d = dst[e];
            int b = d >> SB_BITS;
            kk[k] = b;
            pk[k] = ((unsigned)(d & (SBLK - 1)) << 17) | (unsigned)s;
            rk[k] = atomicAdd(&cnt[b], 1);
        } else kk[k] = -1;
    }
    __syncthreads();
    if (threadIdx.x == 0) {
        int acc = 0;
        for (int b = 0; b < nb; b++) { pos[b] = acc; acc += cnt[b]; }
    }
    __syncthreads();
    if (threadIdx.x < nb && cnt[threadIdx.x] > 0)
        gbase[threadIdx.x] = atomicAdd(&gcurA[threadIdx.x * GSTRIDE], cnt[threadIdx.x]);
    __syncthreads();
#pragma unroll
    for (int k = 0; k < PT_K; k++) {
        if (kk[k] >= 0) {
            int idx = pos[kk[k]] + rk[k];
            reorder[idx] = pk[k];
            bbk[idx] = (unsigned char)kk[k];
        }
    }
    __syncthreads();
    for (int idx = threadIdx.x; idx < nE; idx += PT_THREADS) {
        int b = bbk[idx];
        int g = gbase[b] + (idx - pos[b]);
        if (g < capA) bucketsA[(size_t)b * capA + g] = reorder[idx];
    }
}

// ---------------- pass B: bin bucket rows into 16-dst sub-buckets ------------
// out payload: (src17<<4) | d4
__global__ void k_passB(const unsigned* __restrict__ bucketsA, const int* __restrict__ gcurA,
                        unsigned* __restrict__ bucketsB, int* __restrict__ gcurB,
                        int capA, int capSub, int tilesB) {
    int j = blockIdx.x / tilesB;
    int tile = blockIdx.x - j * tilesB;
    int cnt_j = min(gcurA[j * GSTRIDE], capA);
    int tb = tile * PT_EDGES;
    if (tb >= cnt_j) return;                    // block-uniform
    int nE = min(PT_EDGES, cnt_j - tb);
    __shared__ int cnt[SUBS];
    __shared__ int pos[SUBS];
    __shared__ int gb[SUBS];
    __shared__ unsigned reorder[PT_EDGES];
    __shared__ unsigned char bbk[PT_EDGES];
    if (threadIdx.x < SUBS) cnt[threadIdx.x] = 0;
    __syncthreads();
    const unsigned* in = bucketsA + (size_t)j * capA + tb;
    int kk[PT_K]; int rk[PT_K]; unsigned pk[PT_K];
#pragma unroll
    for (int k = 0; k < PT_K; k++) {
        int e = k * PT_THREADS + threadIdx.x;
        if (e < nE) {
            unsigned p = in[e];
            int dloc = (int)(p >> 17);
            int s = dloc >> 4;
            kk[k] = s;
            pk[k] = ((p & 0x1FFFFu) << 4) | (unsigned)(dloc & 15);
            rk[k] = atomicAdd(&cnt[s], 1);
        } else kk[k] = -1;
    }
    __syncthreads();
    if (threadIdx.x == 0) {
        int acc = 0;
        for (int s = 0; s < SUBS; s++) { pos[s] = acc; acc += cnt[s]; }
    }
    __syncthreads();
    if (threadIdx.x < SUBS && cnt[threadIdx.x] > 0)
        gb[threadIdx.x] = atomicAdd(&gcurB[j * SUBS + threadIdx.x], cnt[threadIdx.x]);
    __syncthreads();
#pragma unroll
    for (int k = 0; k < PT_K; k++) {
        if (kk[k] >= 0) {
            int idx = pos[kk[k]] + rk[k];
            reorder[idx] = pk[k];
            bbk[idx] = (unsigned char)kk[k];
        }
    }
    __syncthreads();
    for (int idx = threadIdx.x; idx < nE; idx += PT_THREADS) {
        int s = bbk[idx];
        int g = gb[s] + (idx - pos[s]);
        if (g < capSub) bucketsB[(size_t)(j * SUBS + s) * capSub + g] = reorder[idx];
    }
}

// ---------------- agg1 + fused encode ---------------------------------------
// u1=Wp_rel·wd_rel, u2=Wp_rel·wd_root, v1=Wp_root·wd_rel, v2=Wp_root·wd_root
__global__ void __launch_bounds__(256)
k_agg1enc(const unsigned* __restrict__ bk2, const int* __restrict__ gcurB,
          const float* __restrict__ x,
          const float* __restrict__ ewrel, const float* __restrict__ ewroot,
          const float* __restrict__ eb,
          const float* __restrict__ pwrel, const float* __restrict__ pwroot,
          const float* __restrict__ dwrel, const float* __restrict__ dwroot,
          float* __restrict__ SAB, float* __restrict__ G1, float* __restrict__ G2,
          int capSub, int N) {
    __shared__ float P[4 * 16 * ROWP];
    __shared__ float su1[HID], su2[HID], sv1[HID], sv2[HID];
    __shared__ float swr[HID], swo[HID], sbb[HID];
    int t = threadIdx.x;
    if (t < 64) {
        int k = t & 15, w = t >> 4;
        const float* M  = (w < 2) ? pwrel : pwroot;
        const float* vv = ((w & 1) == 0) ? dwrel : dwroot;
        float acc = 0.f;
        for (int h = 0; h < HID; h++) acc += M[k * HID + h] * vv[h];
        if (w == 0) su1[k] = acc;
        else if (w == 1) su2[k] = acc;
        else if (w == 2) sv1[k] = acc;
        else sv2[k] = acc;
    }
    if (t < HID) { swr[t] = ewrel[t]; swo[t] = ewroot[t]; sbb[t] = eb[t]; }
    int wv = t >> 6, lane = t & 63;
    int q = blockIdx.x * 4 + wv;
    float* p = P + wv * 16 * ROWP;
#pragma unroll
    for (int d = 0; d < 16; d++) p[d * ROWP + lane] = 0.f;
    __syncthreads();
    int cnt = min(gcurB[q], capSub);
    const unsigned* bk = bk2 + (size_t)q * capSub;
    int e = lane;
    for (; e + 64 < cnt; e += 128) {
        unsigned pk0 = bk[e], pk1 = bk[e + 64];
        float v0 = x[pk0 >> 4], v1 = x[pk1 >> 4];
        p[(int)(pk0 & 15) * ROWP + lane] += v0;
        p[(int)(pk1 & 15) * ROWP + lane] += v1;
    }
    if (e < cnt) { unsigned pk = bk[e]; p[(int)(pk & 15) * ROWP + lane] += x[pk >> 4]; }
    __builtin_amdgcn_wave_barrier();
    int d = lane & 15, c0 = (lane >> 4) * 16;
    float s = 0.f;
#pragma unroll
    for (int k = 0; k < 16; k++) s += p[d * ROWP + c0 + k];
    s += __shfl_xor(s, 16);
    s += __shfl_xor(s, 32);
    if (lane < 16) {
        int n = q * 16 + lane;
        if (n < N) {
            float a1 = s, xi = x[n];
            float sa = 0.f, sb = 0.f, g1 = 0.f, g2 = 0.f;
#pragma unroll
            for (int h = 0; h < HID; h++) {
                float z = fmaxf(fmaf(a1, swr[h], fmaf(xi, swo[h], sbb[h])), 0.f);
                sa = fmaf(z, su1[h], sa);
                sb = fmaf(z, su2[h], sb);
                g1 = fmaf(z, sv1[h], g1);
                g2 = fmaf(z, sv2[h], g2);
            }
            ((float2*)SAB)[n] = make_float2(sa, sb);
            G1[n] = g1; G2[n] = g2;
        }
    }
}

// ---------------- agg2 + fused mid ------------------------------------------
__global__ void __launch_bounds__(256)
k_agg2mid(const unsigned* __restrict__ bk2, const int* __restrict__ gcurB,
          const float* __restrict__ SAB,
          const float* __restrict__ G1, const float* __restrict__ G2,
          const float* __restrict__ pb, const float* __restrict__ dwrel,
          const float* __restrict__ dwroot, const float* __restrict__ db,
          float* __restrict__ BETA, float* __restrict__ R,
          int capSub, int N) {
    __shared__ float P[4 * 2 * 16 * ROWP];
    __shared__ float sc1, sc2, sbd;
    int t = threadIdx.x;
    if (t == 0) {
        float c1 = 0.f, c2 = 0.f;
        for (int h = 0; h < HID; h++) { c1 += pb[h] * dwrel[h]; c2 += pb[h] * dwroot[h]; }
        sc1 = c1; sc2 = c2; sbd = db[0];
    }
    int wv = t >> 6, lane = t & 63;
    int q = blockIdx.x * 4 + wv;
    float* pa = P + wv * 2 * 16 * ROWP;
    float* pbn = pa + 16 * ROWP;
#pragma unroll
    for (int d = 0; d < 16; d++) { pa[d * ROWP + lane] = 0.f; pbn[d * ROWP + lane] = 0.f; }
    __syncthreads();
    int cnt = min(gcurB[q], capSub);
    const unsigned* bk = bk2 + (size_t)q * capSub;
    const float2* v2 = (const float2*)SAB;
    int e = lane;
    for (; e + 64 < cnt; e += 128) {
        unsigned pk0 = bk[e], pk1 = bk[e + 64];
        float2 v0 = v2[pk0 >> 4], v1 = v2[pk1 >> 4];
        int a0 = (int)(pk0 & 15) * ROWP + lane;
        int a1 = (int)(pk1 & 15) * ROWP + lane;
        pa[a0] += v0.x; pbn[a0] += v0.y;
        pa[a1] += v1.x; pbn[a1] += v1.y;
    }
    if (e < cnt) {
        unsigned pk = bk[e];
        float2 v = v2[pk >> 4];
        int a = (int)(pk & 15) * ROWP + lane;
        pa[a] += v.x; pbn[a] += v.y;
    }
    __builtin_amdgcn_wave_barrier();
    int d = lane & 15, c0 = (lane >> 4) * 16;
    float sa = 0.f, sb = 0.f;
#pragma unroll
    for (int k = 0; k < 16; k++) {
        sa += pa[d * ROWP + c0 + k];
        sb += pbn[d * ROWP + c0 + k];
    }
    sa += __shfl_xor(sa, 16); sa += __shfl_xor(sa, 32);
    sb += __shfl_xor(sb, 16); sb += __shfl_xor(sb, 32);
    if (lane < 16) {
        int n = q * 16 + lane;
        if (n < N) {
            BETA[n] = sa + G1[n] + sc1;
            R[n]    = sb + G2[n] + sc2 + sbd;
        }
    }
}

// ---------------- agg3 + fused final: out = relu(agg(BETA) + R) --------------
__global__ void __launch_bounds__(256)
k_agg1f(const unsigned* __restrict__ bk2, const int* __restrict__ gcurB,
        const float* __restrict__ val, const float* __restrict__ R,
        float* __restrict__ out, int capSub, int N) {
    __shared__ float P[4 * 16 * ROWP];
    int wv = threadIdx.x >> 6, lane = threadIdx.x & 63;
    int q = blockIdx.x * 4 + wv;
    float* p = P + wv * 16 * ROWP;
#pragma unroll
    for (int d = 0; d < 16; d++) p[d * ROWP + lane] = 0.f;
    int cnt = min(gcurB[q], capSub);
    const unsigned* bk = bk2 + (size_t)q * capSub;
    int e = lane;
    for (; e + 64 < cnt; e += 128) {
        unsigned pk0 = bk[e], pk1 = bk[e + 64];
        float v0 = val[pk0 >> 4], v1 = val[pk1 >> 4];
        p[(int)(pk0 & 15) * ROWP + lane] += v0;
        p[(int)(pk1 & 15) * ROWP + lane] += v1;
    }
    if (e < cnt) { unsigned pk = bk[e]; p[(int)(pk & 15) * ROWP + lane] += val[pk >> 4]; }
    __builtin_amdgcn_wave_barrier();
    int d = lane & 15, c0 = (lane >> 4) * 16;
    float s = 0.f;
#pragma unroll
    for (int k = 0; k < 16; k++) s += p[d * ROWP + c0 + k];
    s += __shfl_xor(s, 16);
    s += __shfl_xor(s, 32);
    if (lane < 16) {
        int n = q * 16 + lane;
        if (n < N) out[n] = fmaxf(s + R[n], 0.f);
    }
}

// ---------------- launch ----------------
extern "C" void kernel_launch(void* const* d_in, const int* in_sizes, int n_in,
                              void* d_out, int out_size, void* d_ws, size_t ws_size,
                              hipStream_t stream) {
    const float* x      = (const float*)d_in[0];
    const int*   ei     = (const int*)d_in[1];
    const float* ewrel  = (const float*)d_in[2];
    const float* ewroot = (const float*)d_in[3];
    const float* eb     = (const float*)d_in[4];
    const float* pwrel  = (const float*)d_in[5];
    const float* pwroot = (const float*)d_in[6];
    const float* pb     = (const float*)d_in[7];
    const float* dwrel  = (const float*)d_in[8];
    const float* dwroot = (const float*)d_in[9];
    const float* db     = (const float*)d_in[10];
    float* out = (float*)d_out;

    const int N = in_sizes[0];
    const int E = in_sizes[1] / 2;
    const int* src = ei;
    const int* dst = ei + E;

    const int nb = (N + SBLK - 1) >> SB_BITS;                  // 49
    int capA = ((E / nb + 2048) + PT_EDGES - 1) & ~(PT_EDGES - 1);   // 69632
    const int tilesB = capA / PT_EDGES;                        // 17
    const int nq = nb * SUBS;                                  // 6272 sub-buckets
    int capSub = ((E / nq + 226) + 3) & ~3;                    // ~736 (10 sigma)

    // workspace layout (4-byte words)
    size_t off = 0;
    int* gcurA = (int*)d_ws;                    off += NBMAX * GSTRIDE;   // 1024
    int* gcurB = (int*)d_ws + off;              off += nq;
    const int zeroWords = (int)off;             // cursors contiguous
    off = (off + 255) & ~(size_t)255;
    unsigned* bucketsA = (unsigned*)d_ws + off; off += (size_t)nb * capA;
    unsigned* bucketsB = (unsigned*)d_ws + off; off += (size_t)nq * capSub;
    float* SAB  = (float*)d_ws + off;           off += (size_t)2 * N;
    float* G1   = (float*)d_ws + off;           off += N;
    float* G2   = (float*)d_ws + off;           off += N;
    float* BETA = (float*)d_ws + off;           off += N;
    float* R    = (float*)d_ws + off;           off += N;

    const int ntilesA = (E + PT_EDGES - 1) / PT_EDGES;          // 782
    const int aggBlocks = nq / 4;                               // 1568

    hipLaunchKernelGGL(k_init, dim3((zeroWords + 255) / 256), dim3(256), 0, stream,
                       gcurA, zeroWords);
    hipLaunchKernelGGL(k_passA, dim3(ntilesA), dim3(PT_THREADS), 0, stream,
                       src, dst, bucketsA, gcurA, E, nb, capA);
    hipLaunchKernelGGL(k_passB, dim3(nb * tilesB), dim3(PT_THREADS), 0, stream,
                       bucketsA, gcurA, bucketsB, gcurB, capA, capSub, tilesB);

    // layer 1 agg + encode (writes SAB, G1, G2)
    hipLaunchKernelGGL(k_agg1enc, dim3(aggBlocks), dim3(256), 0, stream,
                       bucketsB, gcurB, x, ewrel, ewroot, eb, pwrel, pwroot,
                       dwrel, dwroot, SAB, G1, G2, capSub, N);
    // layer 2 agg + mid (writes BETA, R)
    hipLaunchKernelGGL(k_agg2mid, dim3(aggBlocks), dim3(256), 0, stream,
                       bucketsB, gcurB, SAB, G1, G2, pb, dwrel, dwroot, db,
                       BETA, R, capSub, N);
    // layer 3 agg + final
    hipLaunchKernelGGL(k_agg1f, dim3(aggBlocks), dim3(256), 0, stream,
                       bucketsB, gcurB, BETA, R, out, capSub, N);
}